// Round 7
// baseline (226.204 us; speedup 1.0000x reference)
//
#include <hip/hip_runtime.h>
#include <hip/hip_bf16.h>
#include <cmath>

#define Bb 8
#define Tt 4096
#define Dd 512
#define Hh 512
#define Mm (Bb*Tt)

// GEMM tiling: small-K 2-phase dbuf, 4 blocks/CU
#define BM 128
#define BN 64
#define BK 32
#define BUFB 20480              // bytes per LDS buffer: (BM + 3*BN)*BK*2

// scan chunking
#define NCHUNK 64
#define CLEN (Tt/NCHUNK)   // 64

typedef unsigned short u16;
typedef unsigned int   u32;
typedef __attribute__((ext_vector_type(8))) short bf16x8;
typedef __attribute__((ext_vector_type(4))) float f32x4;
typedef __attribute__((address_space(3))) char lds_char;

__device__ __forceinline__ u16 f2bf(float f) {
    u32 u = __float_as_uint(f);
    u += 0x7fffu + ((u >> 16) & 1u);   // RNE
    return (u16)(u >> 16);
}
__device__ __forceinline__ float bf2f_lo(u32 p) { return __uint_as_float(p << 16); }
__device__ __forceinline__ float bf2f_hi(u32 p) { return __uint_as_float(p & 0xffff0000u); }

__device__ __forceinline__ void gl2lds16(const void* g, lds_char* l) {
    __builtin_amdgcn_global_load_lds(
        (const __attribute__((address_space(1))) u32*)g,
        (__attribute__((address_space(3))) u32*)l, 16, 0, 0);
}

// ---------------- kernel 0: fp32 -> bf16 convert (x and the 3 W's, one launch) ----------------
__global__ void cvt_all(const float* __restrict__ x,
                        const float* __restrict__ wf, const float* __restrict__ wi,
                        const float* __restrict__ wh,
                        u16* __restrict__ xb, u16* __restrict__ wbuf, int n8x) {
    int i = blockIdx.x * blockDim.x + threadIdx.x;
    const float* in; u16* o; int idx;
    if (i < n8x) { in = x; o = xb; idx = i; }
    else {
        int j = i - n8x;              // 0 .. 3*32768-1
        int g = j >> 15;
        idx = j & 32767;
        in = (g == 0) ? wf : (g == 1) ? wi : wh;
        o = wbuf + (size_t)g * Hh * Dd;
    }
    float4 a = reinterpret_cast<const float4*>(in)[idx*2];
    float4 b = reinterpret_cast<const float4*>(in)[idx*2+1];
    union { u16 u[8]; uint4 v; } r;
    r.u[0]=f2bf(a.x); r.u[1]=f2bf(a.y); r.u[2]=f2bf(a.z); r.u[3]=f2bf(a.w);
    r.u[4]=f2bf(b.x); r.u[5]=f2bf(b.y); r.u[6]=f2bf(b.z); r.u[7]=f2bf(b.w);
    reinterpret_cast<uint4*>(o)[idx] = r.v;
}

// ---------------- kernel 1: fused 3-gate GEMM + gate math + chunk composites ----------------
// Round-3-proven 2-phase dbuf (plain __syncthreads, no vmcnt/sched games), shrunk to
// BK=32 so each buffer is 20 KB -> dbuf 40 KB -> 4 blocks/CU (16 waves): cross-block
// overlap (m114) hides the barrier drain. LDS rows are 64 B, bijective XOR swizzle
// byte ^= ((row&3)<<4) applied on the GLOBAL source (staging) and ds_read address;
// the 4 lane-quarters read 4 distinct 16B columns -> all 8 bank slots covered,
// conflict-free. Epilogue: gate math + packed bf16 FV + fused per-chunk composites.
__global__ __launch_bounds__(256, 4)
void gate_gemm(const u16* __restrict__ xb,      // [Mm][Dd] bf16
               const u16* __restrict__ wb,      // [3][Hh][Dd] bf16
               const float* __restrict__ b_f, const float* __restrict__ b_i,
               const float* __restrict__ b_h,
               u32* __restrict__ FV,            // packed bf16 f | v<<16
               float* __restrict__ Fc, float* __restrict__ Vc)
{
    __shared__ __align__(128) u16 sbuf[2 * BUFB / 2];   // 40 KB

    const int tid  = threadIdx.x;
    const int lane = tid & 63;
    const int w    = tid >> 6;   // 0..3
    const int wm   = w >> 1;     // 0..1 (M)
    const int wn   = w & 1;      // 0..1 (N)

    // XCD-bijective swizzle: 8 consecutive-n blocks per m-panel stay on one XCD
    const int bid = blockIdx.x;
    const int lg  = (bid >> 3) + (bid & 7) * ((int)gridDim.x >> 3);
    const int m0  = (lg >> 3) * BM;
    const int n0  = (lg & 7) * BN;

    // ---- staging addresses (pre-swizzled global source, linear LDS dest) ----
    // Each global_load_lds writes 64 lanes x 16B = 1024B = 16 rows of 64B.
    // lane -> (row = lane>>2, slot = lane&3); source col = (slot ^ (row&3))*16.
    const int lr4  = lane >> 2;
    const int gcol = ((lane & 3) ^ (lr4 & 3)) << 4;
    lds_char* Lb = (lds_char*)&sbuf[0];

    const char* ap[2]; int aOff[2];
    #pragma unroll
    for (int s = 0; s < 2; ++s) {
        ap[s] = (const char*)xb + ((size_t)(m0 + w*32 + s*16 + lr4) << 10) + gcol;
        aOff[s] = (w*2 + s) * 1024;
    }
    const char* wp[3]; int wOff[3];
    #pragma unroll
    for (int s = 0; s < 3; ++s) {
        int jj = w*3 + s;                 // 0..11 over [3][64] rows /16
        int g  = jj >> 2;
        int rg = (jj & 3) * 16;
        wp[s] = (const char*)wb + ((size_t)(g*Hh + n0 + rg + lr4) << 10) + gcol;
        wOff[s] = 8192 + jj * 1024;
    }

    // ---- fragment read offsets (swizzled; row&3 == lane&3 for all frag rows) ----
    const int colx  = (((lane >> 4) ^ (lane & 3)) << 4);
    const int arowb = (wm*64 + (lane & 15)) << 6;   // + mi*1024
    const int wrowb = (wn*32 + (lane & 15)) << 6;   // + ni*1024, + 8192 + g*4096

    f32x4 acc[3][4][2];
    #pragma unroll
    for (int g = 0; g < 3; ++g)
        #pragma unroll
        for (int mi = 0; mi < 4; ++mi)
            #pragma unroll
            for (int ni = 0; ni < 2; ++ni)
                acc[g][mi][ni] = (f32x4){0.f,0.f,0.f,0.f};

    auto STAGE = [&](int bo) {           // 5 global_load_lds per thread-slot set
        #pragma unroll
        for (int s = 0; s < 2; ++s) { gl2lds16(ap[s], Lb + bo + aOff[s]); ap[s] += 2*BK; }
        #pragma unroll
        for (int s = 0; s < 3; ++s) { gl2lds16(wp[s], Lb + bo + wOff[s]); wp[s] += 2*BK; }
    };
    auto COMPUTE = [&](int bo) {
        const char* sA = (const char*)&sbuf[0] + bo;
        bf16x8 a[4];
        #pragma unroll
        for (int mi = 0; mi < 4; ++mi)
            a[mi] = *(const bf16x8*)(sA + arowb + mi*1024 + colx);
        #pragma unroll
        for (int g = 0; g < 3; ++g) {
            bf16x8 w0 = *(const bf16x8*)(sA + 8192 + g*4096 + wrowb + colx);
            bf16x8 w1 = *(const bf16x8*)(sA + 8192 + g*4096 + wrowb + 1024 + colx);
            #pragma unroll
            for (int mi = 0; mi < 4; ++mi) {
                acc[g][mi][0] = __builtin_amdgcn_mfma_f32_16x16x32_bf16(a[mi], w0, acc[g][mi][0], 0,0,0);
                acc[g][mi][1] = __builtin_amdgcn_mfma_f32_16x16x32_bf16(a[mi], w1, acc[g][mi][1], 0,0,0);
            }
        }
    };

    // 16 K-tiles, 2-phase dbuf
    STAGE(0);
    __syncthreads();
    #pragma unroll 1
    for (int i = 0; i < 7; ++i) {
        STAGE(BUFB); COMPUTE(0);    __syncthreads();
        STAGE(0);    COMPUTE(BUFB); __syncthreads();
    }
    STAGE(BUFB); COMPUTE(0); __syncthreads();
    COMPUTE(BUFB);

    // ---- epilogue: gates + FV store + fused chunk composites ----
    // fg = I/(F+I), ig = F/(F+I), F=1+e^-zf, I=1+e^-zi
    const int col = lane & 15;
    const int lg4 = lane >> 4;
    const int rb  = lg4 * 4;
    const int gch = (m0 >> 6) + wm;        // global chunk index == b*NCHUNK+ch

    #pragma unroll
    for (int ni = 0; ni < 2; ++ni) {
        const int h = n0 + wn*32 + ni*16 + col;
        const float bfv = b_f[h], biv = b_i[h], bhv = b_h[h];
        float Fr = 1.0f, Vr = 0.0f;        // running chunk composite
        #pragma unroll
        for (int mi = 0; mi < 4; ++mi) {
            float F4 = 1.0f, V4 = 0.0f;    // local 4-row run composite
            #pragma unroll
            for (int r = 0; r < 4; ++r) {
                const int m = m0 + wm*64 + mi*16 + rb + r;
                float zf = acc[0][mi][ni][r] + bfv;
                float zi = acc[1][mi][ni][r] + biv;
                float zh = acc[2][mi][ni][r] + bhv;
                float ef = __expf(fminf(-zf, 60.0f));
                float ei = __expf(fminf(-zi, 60.0f));
                float rr = __builtin_amdgcn_rcpf(2.0f + ef + ei);
                float fg = (1.0f + ei) * rr;
                float ig = (1.0f + ef) * rr;
                float eh = __expf(fminf(-zh, 60.0f));
                float gv = (zh >= 0.0f) ? (zh + 0.5f) : __builtin_amdgcn_rcpf(1.0f + eh);
                float vv = ig * gv;
                u32 pk = (u32)f2bf(fg) | ((u32)f2bf(vv) << 16);
                FV[(size_t)m * Hh + h] = pk;
                // rounded values so composites match pass3's replay
                float f_ = bf2f_lo(pk), v_ = bf2f_hi(pk);
                V4 = fmaf(f_, V4, v_);
                F4 *= f_;
            }
            // ordered butterfly compose across lane bits 4 and 5
            {
                float Fp = __shfl_xor(F4, 16), Vp = __shfl_xor(V4, 16);
                float Fl = (lane & 16) ? Fp : F4, Vl = (lane & 16) ? Vp : V4;
                float Fh = (lane & 16) ? F4 : Fp, Vh = (lane & 16) ? V4 : Vp;
                F4 = Fh * Fl; V4 = fmaf(Fh, Vl, Vh);
                Fp = __shfl_xor(F4, 32); Vp = __shfl_xor(V4, 32);
                Fl = (lane & 32) ? Fp : F4; Vl = (lane & 32) ? Vp : V4;
                Fh = (lane & 32) ? F4 : Fp; Vh = (lane & 32) ? V4 : Vp;
                F4 = Fh * Fl; V4 = fmaf(Fh, Vl, Vh);
            }
            Vr = fmaf(F4, Vr, V4);
            Fr = F4 * Fr;
        }
        if (lg4 == 0) {
            Fc[(size_t)gch * Hh + h] = Fr;
            Vc[(size_t)gch * Hh + h] = Vr;
        }
    }
}

// ---------------- scan pass 2: scan over chunk composites ----------------
__global__ void scan_pass2(const float* __restrict__ h0,
                           const float* __restrict__ Fc, const float* __restrict__ Vc,
                           float* __restrict__ Hs)
{
    int h = threadIdx.x;      // 512
    int b = blockIdx.x;       // 8
    float x = h0[b * Hh + h];
    float hh = (x >= 0.f) ? (x + 0.5f) : __builtin_amdgcn_rcpf(1.f + __expf(-x));
    #pragma unroll 8
    for (int ch = 0; ch < NCHUNK; ++ch) {
        int ci = (b * NCHUNK + ch) * Hh + h;
        Hs[ci] = hh;
        hh = fmaf(Fc[ci], hh, Vc[ci]);
    }
}

// ---------------- scan pass 3: apply chunks, write outputs ----------------
__global__ void scan_pass3(const u32* __restrict__ FV,
                           const float2* __restrict__ Hs2, float2* __restrict__ out2)
{
    const int t2 = threadIdx.x;
    const int b = blockIdx.x, ch = blockIdx.y;
    const uint2* p = (const uint2*)FV;
    float2 hh = Hs2[(b * NCHUNK + ch) * (Hh/2) + t2];
    size_t base = ((size_t)b * Tt + (size_t)ch * CLEN) * (Hh/2) + t2;
    #pragma unroll 4
    for (int t = 0; t < CLEN; ++t) {
        size_t idx = base + (size_t)t * (Hh/2);
        uint2 fv = p[idx];
        hh.x = fmaf(bf2f_lo(fv.x), hh.x, bf2f_hi(fv.x));
        hh.y = fmaf(bf2f_lo(fv.y), hh.y, bf2f_hi(fv.y));
        out2[idx] = hh;
    }
}

extern "C" void kernel_launch(void* const* d_in, const int* in_sizes, int n_in,
                              void* d_out, int out_size, void* d_ws, size_t ws_size,
                              hipStream_t stream) {
    const float* x   = (const float*)d_in[0];
    const float* h0  = (const float*)d_in[1];
    const float* W_f = (const float*)d_in[2];
    const float* b_f = (const float*)d_in[3];
    const float* W_i = (const float*)d_in[4];
    const float* b_i = (const float*)d_in[5];
    const float* W_h = (const float*)d_in[6];
    const float* b_h = (const float*)d_in[7];
    float* out = (float*)d_out;

    // workspace layout
    char* ws = (char*)d_ws;
    u16*  xb   = (u16*)ws;                                       // 32 MB
    u16*  wbuf = (u16*)(ws + (size_t)Mm * Dd * 2);               // 1.5 MB
    u32*  FV   = (u32*)(ws + (size_t)Mm * Dd * 2 + (size_t)3 * Hh * Dd * 2); // 64 MB
    float* Fc  = (float*)(FV + (size_t)Mm * Hh);                 // 1 MB
    float* Vc  = Fc + (size_t)Bb * NCHUNK * Hh;                  // 1 MB
    float* Hs  = Vc + (size_t)Bb * NCHUNK * Hh;                  // 1 MB

    // 0) converts (x + 3 W's in one launch)
    {
        int n8x = Mm * Dd / 8;                 // 2,097,152
        int total = n8x + 3 * (Hh * Dd / 8);   // + 98,304 = 2,195,456
        cvt_all<<<total / 256, 256, 0, stream>>>(x, W_f, W_i, W_h, xb, wbuf, n8x);
    }

    // 1) fused 3-gate GEMM + gate math + chunk composites
    gate_gemm<<<(Mm / BM) * (Hh / BN), 256, 0, stream>>>(xb, wbuf, b_f, b_i, b_h, FV, Fc, Vc);

    // 2) chunked scan (pass1 fused into gate_gemm epilogue)
    scan_pass2<<<Bb, Hh, 0, stream>>>(h0, Fc, Vc, Hs);
    {
        dim3 g1(Bb, NCHUNK);
        scan_pass3<<<g1, 256, 0, stream>>>(FV, (const float2*)Hs, (float2*)out);
    }
}

// Round 8
// 109.489 us; speedup vs baseline: 2.0660x; 2.0660x over previous
//
#include <hip/hip_runtime.h>
#include <hip/hip_bf16.h>
#include <cmath>

#define Bb 8
#define Tt 4096
#define Dd 512
#define Hh 512
#define Mm (Bb*Tt)

// GEMM tiling (round-3 verified config)
#define BM 128
#define BN 64
#define BK 64
#define BUFB 40960              // bytes per LDS buffer: (BM + 3*BN)*BK*2

// scan chunking
#define NCHUNK 64
#define CLEN (Tt/NCHUNK)   // 64

typedef unsigned short u16;
typedef unsigned int   u32;
typedef __attribute__((ext_vector_type(8))) short bf16x8;
typedef __attribute__((ext_vector_type(4))) float f32x4;
typedef __attribute__((address_space(3))) char lds_char;

__device__ __forceinline__ u16 f2bf(float f) {
    u32 u = __float_as_uint(f);
    u += 0x7fffu + ((u >> 16) & 1u);   // RNE
    return (u16)(u >> 16);
}
__device__ __forceinline__ float bf2f_lo(u32 p) { return __uint_as_float(p << 16); }
__device__ __forceinline__ float bf2f_hi(u32 p) { return __uint_as_float(p & 0xffff0000u); }

__device__ __forceinline__ void gl2lds16(const void* g, lds_char* l) {
    __builtin_amdgcn_global_load_lds(
        (const __attribute__((address_space(1))) u32*)g,
        (__attribute__((address_space(3))) u32*)l, 16, 0, 0);
}

// ---------------- kernel 0: fp32 -> bf16 convert (x and the 3 W's, one launch) ----------------
__global__ void cvt_all(const float* __restrict__ x,
                        const float* __restrict__ wf, const float* __restrict__ wi,
                        const float* __restrict__ wh,
                        u16* __restrict__ xb, u16* __restrict__ wbuf, int n8x) {
    int i = blockIdx.x * blockDim.x + threadIdx.x;
    const float* in; u16* o; int idx;
    if (i < n8x) { in = x; o = xb; idx = i; }
    else {
        int j = i - n8x;              // 0 .. 3*32768-1
        int g = j >> 15;
        idx = j & 32767;
        in = (g == 0) ? wf : (g == 1) ? wi : wh;
        o = wbuf + (size_t)g * Hh * Dd;
    }
    float4 a = reinterpret_cast<const float4*>(in)[idx*2];
    float4 b = reinterpret_cast<const float4*>(in)[idx*2+1];
    union { u16 u[8]; uint4 v; } r;
    r.u[0]=f2bf(a.x); r.u[1]=f2bf(a.y); r.u[2]=f2bf(a.z); r.u[3]=f2bf(a.w);
    r.u[4]=f2bf(b.x); r.u[5]=f2bf(b.y); r.u[6]=f2bf(b.z); r.u[7]=f2bf(b.w);
    reinterpret_cast<uint4*>(o)[idx] = r.v;
}

// ---------------- kernel 1: fused 3-gate GEMM + gate math + chunk composites ----------------
// EXACT round-3 GEMM core (measured best: 60.7us, MfmaUtil 36%, 0 conflicts):
// LDS per buffer: A[128][64] bf16 (16 KB) + W[3][64][64] (24 KB), 128B rows,
// XOR swizzle byte ^= ((row&7)<<4) on GLOBAL source and ds_read address.
// Plain 2-phase dbuf with __syncthreads only. Epilogue additionally fused with
// scan pass1: per-chunk composites via in-register 4-run compose + ordered
// butterfly over lane bits 4/5 (validated r4/r6).
__global__ __launch_bounds__(256, 2)
void gate_gemm(const u16* __restrict__ xb,      // [Mm][Dd] bf16
               const u16* __restrict__ wb,      // [3][Hh][Dd] bf16
               const float* __restrict__ b_f, const float* __restrict__ b_i,
               const float* __restrict__ b_h,
               u32* __restrict__ FV,            // packed bf16 f | v<<16
               float* __restrict__ Fc, float* __restrict__ Vc)
{
    __shared__ __align__(128) u16 sbuf[2 * BUFB / 2];   // 80 KB

    const int tid  = threadIdx.x;
    const int lane = tid & 63;
    const int w    = tid >> 6;
    const int wm   = w >> 1;    // 0..1
    const int wn   = w & 1;     // 0..1

    // XCD-bijective swizzle: consecutive-n blocks stay on one XCD -> A panel L2-hot
    const int bid = blockIdx.x;
    const int lg  = (bid >> 3) + (bid & 7) * ((int)gridDim.x >> 3);
    const int m0  = (lg >> 3) * BM;
    const int n0  = (lg & 7) * BN;

    // ---- staging addresses (pre-swizzled global source, linear LDS dest) ----
    const int lrow = lane >> 3;                       // row within 8-row group
    const int scb  = ((lane & 7) * 16) ^ (lrow << 4); // swizzled col-byte
    lds_char* Lb = (lds_char*)&sbuf[0];

    const char* ap[4]; int aOff[4];
    #pragma unroll
    for (int s = 0; s < 4; ++s) {
        ap[s] = (const char*)xb + ((size_t)(m0 + w*32 + s*8 + lrow) << 10) + scb;
        aOff[s] = (w*4 + s) * 1024;
    }
    const char* wp[6]; int wOff[6];
    #pragma unroll
    for (int s = 0; s < 6; ++s) {
        int jj = w*6 + s;                 // 0..23 over [3][64] rows /8
        int g  = jj >> 3;
        int hg = (jj & 7) * 8 + lrow;
        wp[s] = (const char*)wb + ((size_t)(g*Hh + n0 + hg) << 10) + scb;
        wOff[s] = 16384 + jj * 1024;
    }

    // ---- fragment read offsets (swizzled) ----
    const int arow  = wm*64 + (lane & 15);
    const int wrow  = wn*32 + (lane & 15);
    const int sw    = (lane & 7) << 4;
    int acol[2];
    #pragma unroll
    for (int s = 0; s < 2; ++s)
        acol[s] = ((s*64) | ((lane >> 4) * 16)) ^ sw;

    f32x4 acc[3][4][2];
    #pragma unroll
    for (int g = 0; g < 3; ++g)
        #pragma unroll
        for (int mi = 0; mi < 4; ++mi)
            #pragma unroll
            for (int ni = 0; ni < 2; ++ni)
                acc[g][mi][ni] = (f32x4){0.f,0.f,0.f,0.f};

    auto STAGE = [&](int bo) {           // issue 10 global_load_lds, advance ptrs
        #pragma unroll
        for (int s = 0; s < 4; ++s) { gl2lds16(ap[s], Lb + bo + aOff[s]); ap[s] += 2*BK; }
        #pragma unroll
        for (int s = 0; s < 6; ++s) { gl2lds16(wp[s], Lb + bo + wOff[s]); wp[s] += 2*BK; }
    };
    auto COMPUTE = [&](int bo) {
        const char* sA = (const char*)&sbuf[0] + bo;
        #pragma unroll
        for (int s = 0; s < 2; ++s) {
            bf16x8 a[4];
            #pragma unroll
            for (int mi = 0; mi < 4; ++mi)
                a[mi] = *(const bf16x8*)(sA + ((arow + mi*16) << 7) + acol[s]);
            #pragma unroll
            for (int g = 0; g < 3; ++g) {
                bf16x8 w0 = *(const bf16x8*)(sA + 16384 + g*8192 + (wrow << 7) + acol[s]);
                bf16x8 w1 = *(const bf16x8*)(sA + 16384 + g*8192 + ((wrow + 16) << 7) + acol[s]);
                #pragma unroll
                for (int mi = 0; mi < 4; ++mi) {
                    acc[g][mi][0] = __builtin_amdgcn_mfma_f32_16x16x32_bf16(a[mi], w0, acc[g][mi][0], 0,0,0);
                    acc[g][mi][1] = __builtin_amdgcn_mfma_f32_16x16x32_bf16(a[mi], w1, acc[g][mi][1], 0,0,0);
                }
            }
        }
    };

    // prologue: tile 0 -> buf0
    STAGE(0);
    __syncthreads();

    // steady state: 8 K-tiles total, manually 2-unrolled for static buffer select
    #pragma unroll 1
    for (int i = 0; i < 3; ++i) {
        STAGE(BUFB); COMPUTE(0);    __syncthreads();
        STAGE(0);    COMPUTE(BUFB); __syncthreads();
    }
    STAGE(BUFB); COMPUTE(0); __syncthreads();
    COMPUTE(BUFB);

    // ---- epilogue: gates + FV store + fused chunk composites ----
    // fg = I/(F+I), ig = F/(F+I), F=1+e^-zf, I=1+e^-zi
    const int col = lane & 15;
    const int lg4 = lane >> 4;
    const int rb  = lg4 * 4;
    const int gch = (m0 >> 6) + wm;        // global chunk index == b*NCHUNK+ch

    #pragma unroll
    for (int ni = 0; ni < 2; ++ni) {
        const int h = n0 + wn*32 + ni*16 + col;
        const float bfv = b_f[h], biv = b_i[h], bhv = b_h[h];
        float Fr = 1.0f, Vr = 0.0f;        // running chunk composite
        #pragma unroll
        for (int mi = 0; mi < 4; ++mi) {
            float F4 = 1.0f, V4 = 0.0f;    // local 4-row run composite
            #pragma unroll
            for (int r = 0; r < 4; ++r) {
                const int m = m0 + wm*64 + mi*16 + rb + r;
                float zf = acc[0][mi][ni][r] + bfv;
                float zi = acc[1][mi][ni][r] + biv;
                float zh = acc[2][mi][ni][r] + bhv;
                float ef = __expf(fminf(-zf, 60.0f));
                float ei = __expf(fminf(-zi, 60.0f));
                float rr = __builtin_amdgcn_rcpf(2.0f + ef + ei);
                float fg = (1.0f + ei) * rr;
                float ig = (1.0f + ef) * rr;
                float eh = __expf(fminf(-zh, 60.0f));
                float gv = (zh >= 0.0f) ? (zh + 0.5f) : __builtin_amdgcn_rcpf(1.0f + eh);
                float vv = ig * gv;
                u32 pk = (u32)f2bf(fg) | ((u32)f2bf(vv) << 16);
                FV[(size_t)m * Hh + h] = pk;
                // rounded values so composites match pass3's replay
                float f_ = bf2f_lo(pk), v_ = bf2f_hi(pk);
                V4 = fmaf(f_, V4, v_);
                F4 *= f_;
            }
            // ordered butterfly compose across lane bits 4 and 5
            {
                float Fp = __shfl_xor(F4, 16), Vp = __shfl_xor(V4, 16);
                float Fl = (lane & 16) ? Fp : F4, Vl = (lane & 16) ? Vp : V4;
                float Fh = (lane & 16) ? F4 : Fp, Vh = (lane & 16) ? V4 : Vp;
                F4 = Fh * Fl; V4 = fmaf(Fh, Vl, Vh);
                Fp = __shfl_xor(F4, 32); Vp = __shfl_xor(V4, 32);
                Fl = (lane & 32) ? Fp : F4; Vl = (lane & 32) ? Vp : V4;
                Fh = (lane & 32) ? F4 : Fp; Vh = (lane & 32) ? V4 : Vp;
                F4 = Fh * Fl; V4 = fmaf(Fh, Vl, Vh);
            }
            Vr = fmaf(F4, Vr, V4);
            Fr = F4 * Fr;
        }
        if (lg4 == 0) {
            Fc[(size_t)gch * Hh + h] = Fr;
            Vc[(size_t)gch * Hh + h] = Vr;
        }
    }
}

// ---------------- scan pass 2: scan over chunk composites ----------------
__global__ void scan_pass2(const float* __restrict__ h0,
                           const float* __restrict__ Fc, const float* __restrict__ Vc,
                           float* __restrict__ Hs)
{
    int h = threadIdx.x;      // 512
    int b = blockIdx.x;       // 8
    float x = h0[b * Hh + h];
    float hh = (x >= 0.f) ? (x + 0.5f) : __builtin_amdgcn_rcpf(1.f + __expf(-x));
    #pragma unroll 8
    for (int ch = 0; ch < NCHUNK; ++ch) {
        int ci = (b * NCHUNK + ch) * Hh + h;
        Hs[ci] = hh;
        hh = fmaf(Fc[ci], hh, Vc[ci]);
    }
}

// ---------------- scan pass 3: apply chunks, write outputs ----------------
__global__ void scan_pass3(const u32* __restrict__ FV,
                           const float2* __restrict__ Hs2, float2* __restrict__ out2)
{
    const int t2 = threadIdx.x;
    const int b = blockIdx.x, ch = blockIdx.y;
    const uint2* p = (const uint2*)FV;
    float2 hh = Hs2[(b * NCHUNK + ch) * (Hh/2) + t2];
    size_t base = ((size_t)b * Tt + (size_t)ch * CLEN) * (Hh/2) + t2;
    #pragma unroll 4
    for (int t = 0; t < CLEN; ++t) {
        size_t idx = base + (size_t)t * (Hh/2);
        uint2 fv = p[idx];
        hh.x = fmaf(bf2f_lo(fv.x), hh.x, bf2f_hi(fv.x));
        hh.y = fmaf(bf2f_lo(fv.y), hh.y, bf2f_hi(fv.y));
        out2[idx] = hh;
    }
}

extern "C" void kernel_launch(void* const* d_in, const int* in_sizes, int n_in,
                              void* d_out, int out_size, void* d_ws, size_t ws_size,
                              hipStream_t stream) {
    const float* x   = (const float*)d_in[0];
    const float* h0  = (const float*)d_in[1];
    const float* W_f = (const float*)d_in[2];
    const float* b_f = (const float*)d_in[3];
    const float* W_i = (const float*)d_in[4];
    const float* b_i = (const float*)d_in[5];
    const float* W_h = (const float*)d_in[6];
    const float* b_h = (const float*)d_in[7];
    float* out = (float*)d_out;

    // workspace layout
    char* ws = (char*)d_ws;
    u16*  xb   = (u16*)ws;                                       // 32 MB
    u16*  wbuf = (u16*)(ws + (size_t)Mm * Dd * 2);               // 1.5 MB
    u32*  FV   = (u32*)(ws + (size_t)Mm * Dd * 2 + (size_t)3 * Hh * Dd * 2); // 64 MB
    float* Fc  = (float*)(FV + (size_t)Mm * Hh);                 // 1 MB
    float* Vc  = Fc + (size_t)Bb * NCHUNK * Hh;                  // 1 MB
    float* Hs  = Vc + (size_t)Bb * NCHUNK * Hh;                  // 1 MB

    // 0) converts (x + 3 W's in one launch)
    {
        int n8x = Mm * Dd / 8;                 // 2,097,152
        int total = n8x + 3 * (Hh * Dd / 8);   // + 98,304 = 2,195,456
        cvt_all<<<total / 256, 256, 0, stream>>>(x, W_f, W_i, W_h, xb, wbuf, n8x);
    }

    // 1) fused 3-gate GEMM + gate math + chunk composites
    gate_gemm<<<(Mm / BM) * (Hh / BN), 256, 0, stream>>>(xb, wbuf, b_f, b_i, b_h, FV, Fc, Vc);

    // 2) chunked scan (pass1 fused into gate_gemm epilogue)
    scan_pass2<<<Bb, Hh, 0, stream>>>(h0, Fc, Vc, Hs);
    {
        dim3 g1(Bb, NCHUNK);
        scan_pass3<<<g1, 256, 0, stream>>>(FV, (const float2*)Hs, (float2*)out);
    }
}

// Round 9
// 107.447 us; speedup vs baseline: 2.1053x; 1.0190x over previous
//
#include <hip/hip_runtime.h>
#include <hip/hip_bf16.h>
#include <cmath>

#define Bb 8
#define Tt 4096
#define Dd 512
#define Hh 512
#define Mm (Bb*Tt)

// GEMM tiling (round-3 verified config)
#define BM 128
#define BN 64
#define BK 64
#define BUFB 40960              // bytes per LDS buffer: (BM + 3*BN)*BK*2

// scan chunking
#define NCHUNK 64
#define CLEN (Tt/NCHUNK)   // 64

typedef unsigned short u16;
typedef unsigned int   u32;
typedef __attribute__((ext_vector_type(8))) short bf16x8;
typedef __attribute__((ext_vector_type(4))) float f32x4;
typedef __attribute__((address_space(3))) char lds_char;

__device__ __forceinline__ u16 f2bf(float f) {
    u32 u = __float_as_uint(f);
    u += 0x7fffu + ((u >> 16) & 1u);   // RNE
    return (u16)(u >> 16);
}
__device__ __forceinline__ float bf2f_lo(u32 p) { return __uint_as_float(p << 16); }
__device__ __forceinline__ float bf2f_hi(u32 p) { return __uint_as_float(p & 0xffff0000u); }

__device__ __forceinline__ void gl2lds16(const void* g, lds_char* l) {
    __builtin_amdgcn_global_load_lds(
        (const __attribute__((address_space(1))) u32*)g,
        (__attribute__((address_space(3))) u32*)l, 16, 0, 0);
}

// ---------------- kernel 0: fp32 -> bf16 convert (x and the 3 W's, one launch) ----------------
__global__ void cvt_all(const float* __restrict__ x,
                        const float* __restrict__ wf, const float* __restrict__ wi,
                        const float* __restrict__ wh,
                        u16* __restrict__ xb, u16* __restrict__ wbuf, int n8x) {
    int i = blockIdx.x * blockDim.x + threadIdx.x;
    const float* in; u16* o; int idx;
    if (i < n8x) { in = x; o = xb; idx = i; }
    else {
        int j = i - n8x;              // 0 .. 3*32768-1
        int g = j >> 15;
        idx = j & 32767;
        in = (g == 0) ? wf : (g == 1) ? wi : wh;
        o = wbuf + (size_t)g * Hh * Dd;
    }
    float4 a = reinterpret_cast<const float4*>(in)[idx*2];
    float4 b = reinterpret_cast<const float4*>(in)[idx*2+1];
    union { u16 u[8]; uint4 v; } r;
    r.u[0]=f2bf(a.x); r.u[1]=f2bf(a.y); r.u[2]=f2bf(a.z); r.u[3]=f2bf(a.w);
    r.u[4]=f2bf(b.x); r.u[5]=f2bf(b.y); r.u[6]=f2bf(b.z); r.u[7]=f2bf(b.w);
    reinterpret_cast<uint4*>(o)[idx] = r.v;
}

// ---------------- kernel 1: fused 3-gate GEMM + gate math + chunk composites ----------------
// EXACT round-3 GEMM core (measured best): LDS per buffer A[128][64] bf16 (16 KB)
// + W[3][64][64] (24 KB), 128B rows, XOR swizzle byte ^= ((row&7)<<4) on GLOBAL
// source and ds_read address. Plain 2-phase dbuf with __syncthreads only.
// Epilogue fused with scan pass1 (per-chunk composites via in-register 4-run
// compose + ordered butterfly over lane bits 4/5).
__global__ __launch_bounds__(256, 2)
void gate_gemm(const u16* __restrict__ xb,      // [Mm][Dd] bf16
               const u16* __restrict__ wb,      // [3][Hh][Dd] bf16
               const float* __restrict__ b_f, const float* __restrict__ b_i,
               const float* __restrict__ b_h,
               u32* __restrict__ FV,            // packed bf16 f | v<<16
               float* __restrict__ Fc, float* __restrict__ Vc)
{
    __shared__ __align__(128) u16 sbuf[2 * BUFB / 2];   // 80 KB

    const int tid  = threadIdx.x;
    const int lane = tid & 63;
    const int w    = tid >> 6;
    const int wm   = w >> 1;    // 0..1
    const int wn   = w & 1;     // 0..1

    // XCD-bijective swizzle: consecutive-n blocks stay on one XCD -> A panel L2-hot
    const int bid = blockIdx.x;
    const int lg  = (bid >> 3) + (bid & 7) * ((int)gridDim.x >> 3);
    const int m0  = (lg >> 3) * BM;
    const int n0  = (lg & 7) * BN;

    // ---- staging addresses (pre-swizzled global source, linear LDS dest) ----
    const int lrow = lane >> 3;                       // row within 8-row group
    const int scb  = ((lane & 7) * 16) ^ (lrow << 4); // swizzled col-byte
    lds_char* Lb = (lds_char*)&sbuf[0];

    const char* ap[4]; int aOff[4];
    #pragma unroll
    for (int s = 0; s < 4; ++s) {
        ap[s] = (const char*)xb + ((size_t)(m0 + w*32 + s*8 + lrow) << 10) + scb;
        aOff[s] = (w*4 + s) * 1024;
    }
    const char* wp[6]; int wOff[6];
    #pragma unroll
    for (int s = 0; s < 6; ++s) {
        int jj = w*6 + s;                 // 0..23 over [3][64] rows /8
        int g  = jj >> 3;
        int hg = (jj & 7) * 8 + lrow;
        wp[s] = (const char*)wb + ((size_t)(g*Hh + n0 + hg) << 10) + scb;
        wOff[s] = 16384 + jj * 1024;
    }

    // ---- fragment read offsets (swizzled) ----
    const int arow  = wm*64 + (lane & 15);
    const int wrow  = wn*32 + (lane & 15);
    const int sw    = (lane & 7) << 4;
    int acol[2];
    #pragma unroll
    for (int s = 0; s < 2; ++s)
        acol[s] = ((s*64) | ((lane >> 4) * 16)) ^ sw;

    f32x4 acc[3][4][2];
    #pragma unroll
    for (int g = 0; g < 3; ++g)
        #pragma unroll
        for (int mi = 0; mi < 4; ++mi)
            #pragma unroll
            for (int ni = 0; ni < 2; ++ni)
                acc[g][mi][ni] = (f32x4){0.f,0.f,0.f,0.f};

    auto STAGE = [&](int bo) {           // issue 10 global_load_lds, advance ptrs
        #pragma unroll
        for (int s = 0; s < 4; ++s) { gl2lds16(ap[s], Lb + bo + aOff[s]); ap[s] += 2*BK; }
        #pragma unroll
        for (int s = 0; s < 6; ++s) { gl2lds16(wp[s], Lb + bo + wOff[s]); wp[s] += 2*BK; }
    };
    auto COMPUTE = [&](int bo) {
        const char* sA = (const char*)&sbuf[0] + bo;
        #pragma unroll
        for (int s = 0; s < 2; ++s) {
            bf16x8 a[4];
            #pragma unroll
            for (int mi = 0; mi < 4; ++mi)
                a[mi] = *(const bf16x8*)(sA + ((arow + mi*16) << 7) + acol[s]);
            #pragma unroll
            for (int g = 0; g < 3; ++g) {
                bf16x8 w0 = *(const bf16x8*)(sA + 16384 + g*8192 + (wrow << 7) + acol[s]);
                bf16x8 w1 = *(const bf16x8*)(sA + 16384 + g*8192 + ((wrow + 16) << 7) + acol[s]);
                #pragma unroll
                for (int mi = 0; mi < 4; ++mi) {
                    acc[g][mi][0] = __builtin_amdgcn_mfma_f32_16x16x32_bf16(a[mi], w0, acc[g][mi][0], 0,0,0);
                    acc[g][mi][1] = __builtin_amdgcn_mfma_f32_16x16x32_bf16(a[mi], w1, acc[g][mi][1], 0,0,0);
                }
            }
        }
    };

    // prologue: tile 0 -> buf0
    STAGE(0);
    __syncthreads();

    // steady state: 8 K-tiles total, manually 2-unrolled for static buffer select
    #pragma unroll 1
    for (int i = 0; i < 3; ++i) {
        STAGE(BUFB); COMPUTE(0);    __syncthreads();
        STAGE(0);    COMPUTE(BUFB); __syncthreads();
    }
    STAGE(BUFB); COMPUTE(0); __syncthreads();
    COMPUTE(BUFB);

    // ---- epilogue: gates + FV store + fused chunk composites ----
    // fg = I/(F+I), ig = F/(F+I), F=1+e^-zf, I=1+e^-zi
    const int col = lane & 15;
    const int lg4 = lane >> 4;
    const int rb  = lg4 * 4;
    const int gch = (m0 >> 6) + wm;        // global chunk index == b*NCHUNK+ch

    #pragma unroll
    for (int ni = 0; ni < 2; ++ni) {
        const int h = n0 + wn*32 + ni*16 + col;
        const float bfv = b_f[h], biv = b_i[h], bhv = b_h[h];
        float Fr = 1.0f, Vr = 0.0f;        // running chunk composite
        #pragma unroll
        for (int mi = 0; mi < 4; ++mi) {
            float F4 = 1.0f, V4 = 0.0f;    // local 4-row run composite
            #pragma unroll
            for (int r = 0; r < 4; ++r) {
                const int m = m0 + wm*64 + mi*16 + rb + r;
                float zf = acc[0][mi][ni][r] + bfv;
                float zi = acc[1][mi][ni][r] + biv;
                float zh = acc[2][mi][ni][r] + bhv;
                float ef = __expf(fminf(-zf, 60.0f));
                float ei = __expf(fminf(-zi, 60.0f));
                float rr = __builtin_amdgcn_rcpf(2.0f + ef + ei);
                float fg = (1.0f + ei) * rr;
                float ig = (1.0f + ef) * rr;
                float eh = __expf(fminf(-zh, 60.0f));
                float gv = (zh >= 0.0f) ? (zh + 0.5f) : __builtin_amdgcn_rcpf(1.0f + eh);
                float vv = ig * gv;
                // native RNE bf16 converts (compiler emits v_cvt; m240: don't hand-roll)
                __hip_bfloat16 blo = __float2bfloat16(fg);
                __hip_bfloat16 bhi = __float2bfloat16(vv);
                u32 pk = (u32)*reinterpret_cast<u16*>(&blo) |
                         ((u32)*reinterpret_cast<u16*>(&bhi) << 16);
                FV[(size_t)m * Hh + h] = pk;
                // rounded values so composites match the apply kernel's replay
                float f_ = bf2f_lo(pk), v_ = bf2f_hi(pk);
                V4 = fmaf(f_, V4, v_);
                F4 *= f_;
            }
            // ordered butterfly compose across lane bits 4 and 5
            {
                float Fp = __shfl_xor(F4, 16), Vp = __shfl_xor(V4, 16);
                float Fl = (lane & 16) ? Fp : F4, Vl = (lane & 16) ? Vp : V4;
                float Fh = (lane & 16) ? F4 : Fp, Vh = (lane & 16) ? V4 : Vp;
                F4 = Fh * Fl; V4 = fmaf(Fh, Vl, Vh);
                Fp = __shfl_xor(F4, 32); Vp = __shfl_xor(V4, 32);
                Fl = (lane & 32) ? Fp : F4; Vl = (lane & 32) ? Vp : V4;
                Fh = (lane & 32) ? F4 : Fp; Vh = (lane & 32) ? V4 : Vp;
                F4 = Fh * Fl; V4 = fmaf(Fh, Vl, Vh);
            }
            Vr = fmaf(F4, Vr, V4);
            Fr = F4 * Fr;
        }
        if (lg4 == 0) {
            Fc[(size_t)gch * Hh + h] = Fr;
            Vc[(size_t)gch * Hh + h] = Vr;
        }
    }
}

// ---------------- scan apply: redundant per-block prefix + chunk replay ----------------
// Block (b,ch): computes the prefix h at chunk start by sequentially composing
// Fc/Vc[0..ch) (L2-resident, 2 MB total; bitwise-identical order to the old
// scan_pass2), then replays the chunk from FV writing outputs. No Hs buffer,
// no device-wide serialization behind 8 blocks.
__global__ void scan_apply(const u32* __restrict__ FV,
                           const float* __restrict__ h0,
                           const float2* __restrict__ Fc2, const float2* __restrict__ Vc2,
                           float2* __restrict__ out2)
{
    const int t2 = threadIdx.x;               // h-pair 0..255
    const int b = blockIdx.x, ch = blockIdx.y;

    // g(h_0)
    float2 x0 = reinterpret_cast<const float2*>(h0)[b * (Hh/2) + t2];
    float2 hh;
    hh.x = (x0.x >= 0.f) ? (x0.x + 0.5f) : __builtin_amdgcn_rcpf(1.f + __expf(-x0.x));
    hh.y = (x0.y >= 0.f) ? (x0.y + 0.5f) : __builtin_amdgcn_rcpf(1.f + __expf(-x0.y));

    // prefix over chunk composites [0, ch)
    #pragma unroll 4
    for (int k = 0; k < ch; ++k) {
        int ci = (b * NCHUNK + k) * (Hh/2) + t2;
        float2 F = Fc2[ci];
        float2 V = Vc2[ci];
        hh.x = fmaf(F.x, hh.x, V.x);
        hh.y = fmaf(F.y, hh.y, V.y);
    }

    // replay this chunk
    const uint2* p = (const uint2*)FV;
    size_t base = ((size_t)b * Tt + (size_t)ch * CLEN) * (Hh/2) + t2;
    #pragma unroll 4
    for (int t = 0; t < CLEN; ++t) {
        size_t idx = base + (size_t)t * (Hh/2);
        uint2 fv = p[idx];
        hh.x = fmaf(bf2f_lo(fv.x), hh.x, bf2f_hi(fv.x));
        hh.y = fmaf(bf2f_lo(fv.y), hh.y, bf2f_hi(fv.y));
        out2[idx] = hh;
    }
}

extern "C" void kernel_launch(void* const* d_in, const int* in_sizes, int n_in,
                              void* d_out, int out_size, void* d_ws, size_t ws_size,
                              hipStream_t stream) {
    const float* x   = (const float*)d_in[0];
    const float* h0  = (const float*)d_in[1];
    const float* W_f = (const float*)d_in[2];
    const float* b_f = (const float*)d_in[3];
    const float* W_i = (const float*)d_in[4];
    const float* b_i = (const float*)d_in[5];
    const float* W_h = (const float*)d_in[6];
    const float* b_h = (const float*)d_in[7];
    float* out = (float*)d_out;

    // workspace layout
    char* ws = (char*)d_ws;
    u16*  xb   = (u16*)ws;                                       // 32 MB
    u16*  wbuf = (u16*)(ws + (size_t)Mm * Dd * 2);               // 1.5 MB
    u32*  FV   = (u32*)(ws + (size_t)Mm * Dd * 2 + (size_t)3 * Hh * Dd * 2); // 64 MB
    float* Fc  = (float*)(FV + (size_t)Mm * Hh);                 // 1 MB
    float* Vc  = Fc + (size_t)Bb * NCHUNK * Hh;                  // 1 MB

    // 0) converts (x + 3 W's in one launch)
    {
        int n8x = Mm * Dd / 8;                 // 2,097,152
        int total = n8x + 3 * (Hh * Dd / 8);   // + 98,304 = 2,195,456
        cvt_all<<<total / 256, 256, 0, stream>>>(x, W_f, W_i, W_h, xb, wbuf, n8x);
    }

    // 1) fused 3-gate GEMM + gate math + chunk composites
    gate_gemm<<<(Mm / BM) * (Hh / BN), 256, 0, stream>>>(xb, wbuf, b_f, b_i, b_h, FV, Fc, Vc);

    // 2) fused prefix + apply (pass2 eliminated)
    {
        dim3 g1(Bb, NCHUNK);
        scan_apply<<<g1, 256, 0, stream>>>(FV, h0, (const float2*)Fc, (const float2*)Vc, (float2*)out);
    }
}